// Round 8
// baseline (217.997 us; speedup 1.0000x reference)
//
#include <hip/hip_runtime.h>
#include <math.h>

#define NB 2
#define NL 2048
#define ND 1024
#define NH 16
#define NDH 64
static constexpr float QSCL = 0.18033688011112042f;   // (1/sqrt(64)) * log2(e)

typedef short          bhalf8 __attribute__((ext_vector_type(8)));   // 8 bf16 (4 VGPR)
typedef unsigned short ush8   __attribute__((ext_vector_type(8)));
typedef unsigned short ush4   __attribute__((ext_vector_type(4)));
typedef float          f32x4  __attribute__((ext_vector_type(4)));

#define MFMA_BF16(a, b, c) __builtin_amdgcn_mfma_f32_16x16x32_bf16(a, b, c, 0, 0, 0)

__device__ __forceinline__ unsigned short f2bf(float f) {
    unsigned u = __float_as_uint(f);
    u += 0x7FFF + ((u >> 16) & 1);           // RNE
    return (unsigned short)(u >> 16);
}
__device__ __forceinline__ float bf2f(unsigned short s) {
    return __uint_as_float((unsigned)s << 16);
}
// pack two floats to two bf16 in ONE dword: [15:0]=lo, [31:16]=hi
__device__ __forceinline__ unsigned pack_bf16(float lo, float hi) {
    unsigned a = __float_as_uint(lo) + 0x8000u;
    unsigned b = __float_as_uint(hi) + 0x8000u;
    return __builtin_amdgcn_perm(b, a, 0x07060302u);
}
// async global->LDS, 16B per lane. lds dest must be wave-uniform base (+lane*16).
__device__ __forceinline__ void gload16(const unsigned short* g, unsigned short* l) {
    __builtin_amdgcn_global_load_lds(
        (const __attribute__((address_space(1))) unsigned int*)(const void*)g,
        (__attribute__((address_space(3))) unsigned int*)(void*)l,
        16, 0, 0);
}
// raw-barrier syncs: vmcnt drain (staging ready) / lgkm drain only (LDS stores visible,
// in-flight global_load_lds prefetch NOT drained). sched_barrier stops compiler motion.
__device__ __forceinline__ void sync_vm0() {
    asm volatile("s_waitcnt vmcnt(0)" ::: "memory");
    __builtin_amdgcn_sched_barrier(0);
    __builtin_amdgcn_s_barrier();
    __builtin_amdgcn_sched_barrier(0);
}
__device__ __forceinline__ void sync_lgkm0() {
    asm volatile("s_waitcnt lgkmcnt(0)" ::: "memory");
    __builtin_amdgcn_sched_barrier(0);
    __builtin_amdgcn_s_barrier();
    __builtin_amdgcn_sched_barrier(0);
}

// ---------------------------------------------------------------------------
// Convert 1: fp32->bf16 for x (4M elems) then WO (1M elems).
// ---------------------------------------------------------------------------
__global__ __launch_bounds__(256) void k_cvt(
    const float* __restrict__ x, const float* __restrict__ WO,
    unsigned short* __restrict__ xb, unsigned short* __restrict__ wob)
{
    size_t u = (size_t)blockIdx.x * 256 + threadIdx.x;
    const float* src; unsigned short* dst; size_t off;
    if (u < 524288) { src = x;  dst = xb;  off = u * 8; }
    else            { src = WO; dst = wob; off = (u - 524288) * 8; }
    float4 a = *(const float4*)(src + off);
    float4 b = *(const float4*)(src + off + 4);
    uint4 o;
    o.x = pack_bf16(a.x, a.y); o.y = pack_bf16(a.z, a.w);
    o.z = pack_bf16(b.x, b.y); o.w = pack_bf16(b.z, b.w);
    *(uint4*)(dst + off) = o;
}

// ---------------------------------------------------------------------------
// Convert 2: Wq/Wk/Wv [h][1024 d][64 dh] fp32 -> Wtb [qkv][h][64 dh][1024 d] bf16.
// Wq additionally scaled by QSCL so QK^T is directly the exp2 argument.
// ---------------------------------------------------------------------------
__global__ __launch_bounds__(256) void k_cvt_wt(
    const float* __restrict__ Wq, const float* __restrict__ Wk,
    const float* __restrict__ Wv, unsigned short* __restrict__ Wtb)
{
    __shared__ unsigned short T[64][72];
    const int d0  = blockIdx.x * 64;
    const int qkv = blockIdx.y >> 4;
    const int h   = blockIdx.y & 15;
    const float* W = (qkv == 0 ? Wq : (qkv == 1 ? Wk : Wv)) + (size_t)h * (ND * NDH);
    const float sc = (qkv == 0) ? QSCL : 1.0f;
    const int t = threadIdx.x;
#pragma unroll
    for (int p = 0; p < 4; ++p) {
        int u  = t + p * 256;
        int dr = u >> 4;
        int c4 = (u & 15) * 4;
        float4 v = *(const float4*)(W + (size_t)(d0 + dr) * NDH + c4);
        T[c4 + 0][dr] = f2bf(v.x * sc);
        T[c4 + 1][dr] = f2bf(v.y * sc);
        T[c4 + 2][dr] = f2bf(v.z * sc);
        T[c4 + 3][dr] = f2bf(v.w * sc);
    }
    __syncthreads();
    unsigned short* outp = Wtb + (size_t)(qkv * NH + h) * NDH * ND;
#pragma unroll
    for (int p = 0; p < 2; ++p) {
        int u  = t + p * 256;
        int dh = u >> 3;
        int sg = (u & 7) * 8;
        *(ush8*)(outp + (size_t)dh * ND + d0 + sg) = *(ush8*)&T[dh][sg];
    }
}

// ---------------------------------------------------------------------------
// QKV projection as ONE GEMM: out[m][n] = sum_d xb[m][d]*Wtb[n][d],
// m=4096, n=3072, 128x128 tile, BK=64, 4 waves. 2-phase pipelined staging.
// ---------------------------------------------------------------------------
__global__ __launch_bounds__(256, 2) void k_qkv_mfma(
    const unsigned short* __restrict__ xb, const unsigned short* __restrict__ Wtb,
    const float* __restrict__ bq, const float* __restrict__ bk,
    const float* __restrict__ bv,
    unsigned short* __restrict__ Qb, unsigned short* __restrict__ Kb,
    unsigned short* __restrict__ Vtb)
{
    constexpr int CH = 128 * 64;
    __shared__ unsigned short LB[4 * CH];   // As0|As1|Bs0|Bs1; TS reuses LB[0..2CH)

    const int mt = blockIdx.x;   // 0..31
    const int nt = blockIdx.y;   // 0..23
    const int qkv = nt >> 3;
    const int t = threadIdx.x, w = t >> 6, lane = t & 63;
    const int lr = lane & 15, lg = lane >> 4;
    const int wm = (w >> 1) * 64, wn = (w & 1) * 64;
    const int swz = (lr & 7) << 3;
    const int rA = lane >> 3, cg = (lane & 7) * 8;

    auto stage = [&](int k0, int buf) {
#pragma unroll
        for (int i = 0; i < 4; ++i) {
            int c  = w * 4 + i;
            int r  = c * 8 + rA;
            int gc = cg ^ ((r & 7) << 3);
            gload16(xb  + (size_t)(mt * 128 + r) * ND + k0 + gc, LB + buf * CH + c * 512);
            gload16(Wtb + (size_t)(nt * 128 + r) * ND + k0 + gc, LB + (2 + buf) * CH + c * 512);
        }
    };

    f32x4 acc[4][4] = {};
    stage(0, 0);
    sync_vm0();

    int cur = 0;
    for (int k0 = 0; k0 < ND; k0 += 64) {
        if (k0 + 64 < ND) stage(k0 + 64, cur ^ 1);
        const unsigned short* Ac = LB + cur * CH;
        const unsigned short* Bc = LB + (2 + cur) * CH;

        bhalf8 av[4][2], bw[4][2];
#pragma unroll
        for (int f = 0; f < 4; ++f)
#pragma unroll
            for (int ks = 0; ks < 2; ++ks) {
                int c = (ks * 32 + lg * 8) ^ swz;
                av[f][ks] = *(const bhalf8*)&Ac[(wm + f * 16 + lr) * 64 + c];
                bw[f][ks] = *(const bhalf8*)&Bc[(wn + f * 16 + lr) * 64 + c];
            }
#pragma unroll
        for (int mf = 0; mf < 4; ++mf)
#pragma unroll
            for (int nf = 0; nf < 4; ++nf) {
                acc[mf][nf] = MFMA_BF16(av[mf][0], bw[nf][0], acc[mf][nf]);
                acc[mf][nf] = MFMA_BF16(av[mf][1], bw[nf][1], acc[mf][nf]);
            }
        sync_vm0();
        cur ^= 1;
    }

    const float* bias = (qkv == 0 ? bq : (qkv == 1 ? bk : bv));
    const float bsc = (qkv == 0) ? QSCL : 1.0f;
    const int nb = (nt & 7) * 128;
    float bi[4];
#pragma unroll
    for (int nf = 0; nf < 4; ++nf) bi[nf] = bias[nb + wn + nf * 16 + lr] * bsc;

    unsigned short* TS = LB;            // [128][128], xor-swizzled

    if (qkv < 2) {
#pragma unroll
        for (int mf = 0; mf < 4; ++mf)
#pragma unroll
            for (int nf = 0; nf < 4; ++nf)
#pragma unroll
                for (int r = 0; r < 4; ++r) {
                    int m = wm + mf * 16 + lg * 4 + r;
                    int n = (wn + nf * 16 + lr) ^ ((m & 7) << 3);
                    TS[m * 128 + n] = f2bf(acc[mf][nf][r] + bi[nf]);
                }
        __syncthreads();
        unsigned short* outp = (qkv == 0 ? Qb : Kb);
#pragma unroll
        for (int p = 0; p < 8; ++p) {
            int u = t + p * 256;
            int r = u >> 4, sg = (u & 15) * 8;
            ush8 v = *(const ush8*)&TS[r * 128 + (sg ^ ((r & 7) << 3))];
            int m = mt * 128 + r;
            int b = m >> 11, l = m & (NL - 1);
            int n = nb + sg;
            int h = n >> 6, dh = n & 63;
            *(ush8*)(outp + ((size_t)(b * NH + h) * NL + l) * NDH + dh) = v;
        }
    } else {
#pragma unroll
        for (int mf = 0; mf < 4; ++mf)
#pragma unroll
            for (int nf = 0; nf < 4; ++nf) {
                int n = wn + nf * 16 + lr;
                int mc = (wm + mf * 16 + lg * 4) ^ ((n & 7) << 3);
                ush4 pk;
#pragma unroll
                for (int r = 0; r < 4; ++r) pk[r] = f2bf(acc[mf][nf][r] + bi[nf]);
                *(ush4*)&TS[n * 128 + mc] = pk;
            }
        __syncthreads();
#pragma unroll
        for (int p = 0; p < 8; ++p) {
            int u = t + p * 256;
            int r = u >> 4, sg = (u & 15) * 8;
            ush8 v = *(const ush8*)&TS[r * 128 + (sg ^ ((r & 7) << 3))];
            int n = nb + r;
            int h = n >> 6, dh = n & 63;
            int m0 = mt * 128 + sg;
            int b = m0 >> 11, l0 = m0 & (NL - 1);
            *(ush8*)(Vtb + ((size_t)(b * NH + h) * NDH + dh) * NL + l0) = v;
        }
    }
}

// ---------------------------------------------------------------------------
// Column stats + V prescale. 512 thr, 8 waves = 4 jg (32 j) x 2 ig (32 i).
// K-frags hoisted; Q streamed double-buffered (2-phase pipeline).
// Z[bh][j] = sum_i exp2(Qs_i.K_j); then Vt[bh][dh][j] *= 1/Z_j in place.
// ---------------------------------------------------------------------------
__global__ __launch_bounds__(512) void k_colsum_mfma(
    const unsigned short* __restrict__ Qb, const unsigned short* __restrict__ Kb,
    unsigned short* __restrict__ Vtb)
{
    constexpr int CQ = 64 * 64;
    __shared__ unsigned short Ks[128 * 64];   // [j][d], xor-swz (staged once)
    __shared__ unsigned short Qs[2 * CQ];     // [i][d], xor-swz, double-buffered
    __shared__ float zpart[2][128];
    __shared__ float rzbuf[128];

    const int jt = blockIdx.x;    // 0..15
    const int bh = blockIdx.y;    // 0..31
    const unsigned short* Qp = Qb + (size_t)bh * NL * NDH;
    const unsigned short* Kp = Kb + (size_t)bh * NL * NDH;
    const int t = threadIdx.x, w = t >> 6, lane = t & 63;
    const int lr = lane & 15, lg = lane >> 4;
    const int jg = w & 3;    // 32-j group
    const int ig = w >> 2;   // 32-i group
    const int swz = (lr & 7) << 3;
    const int rA = lane >> 3, cg = (lane & 7) * 8;

    // prologue: K tile (2/wave) + Q tile 0 (1/wave)
#pragma unroll
    for (int i = 0; i < 2; ++i) {
        int c  = w * 2 + i;
        int r  = c * 8 + rA;
        int gc = cg ^ ((r & 7) << 3);
        gload16(Kp + (size_t)(jt * 128 + r) * NDH + gc, &Ks[c * 512]);
    }
    {
        int r  = w * 8 + rA;
        int gc = cg ^ ((r & 7) << 3);
        gload16(Qp + (size_t)r * NDH + gc, Qs + w * 512);
    }
    sync_vm0();

    // hoist K fragments (loop-invariant)
    bhalf8 kf[2][2];
#pragma unroll
    for (int jf = 0; jf < 2; ++jf)
#pragma unroll
        for (int ks = 0; ks < 2; ++ks)
            kf[jf][ks] = *(const bhalf8*)&Ks[(jg * 32 + jf * 16 + lr) * 64 +
                                            ((ks * 32 + lg * 8) ^ swz)];

    float zacc[2][4] = {};
    int cur = 0;
    for (int it = 0; it < 32; ++it) {
        if (it + 1 < 32) {
            int r  = w * 8 + rA;
            int gc = cg ^ ((r & 7) << 3);
            gload16(Qp + (size_t)((it + 1) * 64 + r) * NDH + gc, Qs + (cur ^ 1) * CQ + w * 512);
        }
        const unsigned short* Qc = Qs + cur * CQ;
#pragma unroll
        for (int ii = 0; ii < 2; ++ii) {
            bhalf8 q0 = *(const bhalf8*)&Qc[(ig * 32 + ii * 16 + lr) * 64 + ((lg * 8) ^ swz)];
            bhalf8 q1 = *(const bhalf8*)&Qc[(ig * 32 + ii * 16 + lr) * 64 + ((32 + lg * 8) ^ swz)];
#pragma unroll
            for (int jf = 0; jf < 2; ++jf) {
                f32x4 s = {};
                s = MFMA_BF16(kf[jf][0], q0, s);
                s = MFMA_BF16(kf[jf][1], q1, s);
#pragma unroll
                for (int r = 0; r < 4; ++r) zacc[jf][r] += __builtin_amdgcn_exp2f(s[r]);
            }
        }
        sync_vm0();
        cur ^= 1;
    }

    // reduce over the 16 lanes holding different i, then across ig via LDS
#pragma unroll
    for (int jf = 0; jf < 2; ++jf)
#pragma unroll
        for (int r = 0; r < 4; ++r) {
            float v = zacc[jf][r];
            v += __shfl_xor(v, 1);
            v += __shfl_xor(v, 2);
            v += __shfl_xor(v, 4);
            v += __shfl_xor(v, 8);
            if (lr == 0) zpart[ig][jg * 32 + jf * 16 + lg * 4 + r] = v;
        }
    __syncthreads();
    if (t < 128) rzbuf[t] = 1.0f / (zpart[0][t] + zpart[1][t]);
    __syncthreads();

    // scale Vt[bh][0..63][jt*128 .. +128) in place: 512 thr x 16 elems
    unsigned short* Vp = Vtb + (size_t)bh * NDH * NL + jt * 128;
    {
        int dh = t >> 3, jj = (t & 7) * 16;
        unsigned short* vp = Vp + (size_t)dh * NL + jj;
        ush8 v0 = *(const ush8*)vp;
        ush8 v1 = *(const ush8*)(vp + 8);
        float4 z0 = *(const float4*)&rzbuf[jj];
        float4 z1 = *(const float4*)&rzbuf[jj + 4];
        float4 z2 = *(const float4*)&rzbuf[jj + 8];
        float4 z3 = *(const float4*)&rzbuf[jj + 12];
        uint4 o0, o1;
        o0.x = pack_bf16(bf2f(v0[0]) * z0.x, bf2f(v0[1]) * z0.y);
        o0.y = pack_bf16(bf2f(v0[2]) * z0.z, bf2f(v0[3]) * z0.w);
        o0.z = pack_bf16(bf2f(v0[4]) * z1.x, bf2f(v0[5]) * z1.y);
        o0.w = pack_bf16(bf2f(v0[6]) * z1.z, bf2f(v0[7]) * z1.w);
        o1.x = pack_bf16(bf2f(v1[0]) * z2.x, bf2f(v1[1]) * z2.y);
        o1.y = pack_bf16(bf2f(v1[2]) * z2.z, bf2f(v1[3]) * z2.w);
        o1.z = pack_bf16(bf2f(v1[4]) * z3.x, bf2f(v1[5]) * z3.y);
        o1.w = pack_bf16(bf2f(v1[6]) * z3.z, bf2f(v1[7]) * z3.w);
        *(uint4*)vp = o0;
        *(uint4*)(vp + 8) = o1;
    }
}

// ---------------------------------------------------------------------------
// O[i][dh] = sum_j exp2(S_ij) * Vscaled[j][dh]. 512 thr, 8 waves.
// S phase: 8 waves as 2 jg x 4 ig, Q-frags in regs. PV: 4 waves x (32i,64dh).
// K/Vt double-buffered, 2-phase pipeline; mid barrier drains lgkm only.
// ---------------------------------------------------------------------------
__global__ __launch_bounds__(512) void k_av_mfma(
    const unsigned short* __restrict__ Qb, const unsigned short* __restrict__ Kb,
    const unsigned short* __restrict__ Vtb, unsigned short* __restrict__ AOb)
{
    constexpr int CK = 64 * 64;
    __shared__ unsigned short Qs[128 * 64];   // [i][d]  xor-swz (staged once)
    __shared__ unsigned short Ks[2 * CK];     // [j][d]  xor-swz dbuf
    __shared__ unsigned short Vts[2 * CK];    // [dh][j] xor-swz dbuf (prescaled)
    __shared__ unsigned short Ps[128 * 64];   // [i][j]  xor-swz

    const int it = blockIdx.x;   // 0..15
    const int bh = blockIdx.y;   // 0..31
    const int b = bh >> 4, h = bh & 15;
    const unsigned short* Qp = Qb  + (size_t)bh * NL * NDH;
    const unsigned short* Kp = Kb  + (size_t)bh * NL * NDH;
    const unsigned short* Vp = Vtb + (size_t)bh * NDH * NL;

    const int t = threadIdx.x, w = t >> 6, lane = t & 63;
    const int lr = lane & 15, lg = lane >> 4;
    const int jgS = w & 1;    // S: 32-j half
    const int igS = w >> 1;   // S: 32-i group
    const int swz = (lr & 7) << 3;
    const int rA = lane >> 3, cg = (lane & 7) * 8;

    auto stageKV = [&](int jt, int buf) {
        int r  = w * 8 + rA;
        int gc = cg ^ ((r & 7) << 3);
        gload16(Kp + (size_t)(jt * 64 + r) * NDH + gc, Ks  + buf * CK + w * 512);
        gload16(Vp + (size_t)r * NL + jt * 64 + gc,    Vts + buf * CK + w * 512);
    };

    // prologue: Q (2/wave) + K/Vt tile 0 (2/wave)
#pragma unroll
    for (int i = 0; i < 2; ++i) {
        int c  = w * 2 + i;
        int r  = c * 8 + rA;
        int gc = cg ^ ((r & 7) << 3);
        gload16(Qp + (size_t)(it * 128 + r) * NDH + gc, &Qs[c * 512]);
    }
    stageKV(0, 0);
    sync_vm0();

    // hoist Q fragments (loop-invariant)
    bhalf8 qf[2][2];
#pragma unroll
    for (int ii = 0; ii < 2; ++ii)
#pragma unroll
        for (int ks = 0; ks < 2; ++ks)
            qf[ii][ks] = *(const bhalf8*)&Qs[(igS * 32 + ii * 16 + lr) * 64 +
                                            ((ks * 32 + lg * 8) ^ swz)];

    f32x4 oacc[2][4] = {};   // used by waves 0..3 (PV)
    int cur = 0;

    for (int jt = 0; jt < 32; ++jt) {
        if (jt + 1 < 32) stageKV(jt + 1, cur ^ 1);

        // S phase on Ks[cur]
        const unsigned short* Kc = Ks + cur * CK;
#pragma unroll
        for (int jf = 0; jf < 2; ++jf) {
            bhalf8 k0 = *(const bhalf8*)&Kc[(jgS * 32 + jf * 16 + lr) * 64 + ((lg * 8) ^ swz)];
            bhalf8 k1 = *(const bhalf8*)&Kc[(jgS * 32 + jf * 16 + lr) * 64 + ((32 + lg * 8) ^ swz)];
#pragma unroll
            for (int ii = 0; ii < 2; ++ii) {
                f32x4 s = {};
                s = MFMA_BF16(k0, qf[ii][0], s);
                s = MFMA_BF16(k1, qf[ii][1], s);
                uint2 pk;
                pk.x = pack_bf16(__builtin_amdgcn_exp2f(s[0]), __builtin_amdgcn_exp2f(s[1]));
                pk.y = pack_bf16(__builtin_amdgcn_exp2f(s[2]), __builtin_amdgcn_exp2f(s[3]));
                int i = igS * 32 + ii * 16 + lr;
                *(uint2*)&Ps[i * 64 + ((jgS * 32 + jf * 16 + lg * 4) ^ ((i & 7) << 3))] = pk;
            }
        }
        sync_lgkm0();     // Ps visible; prefetch stays in flight

        // PV phase: waves 0..3, wave w owns i [w*32, +32), full j=64
        if (w < 4) {
            const unsigned short* Vc = Vts + cur * CK;
            bhalf8 pa[2][2];
#pragma unroll
            for (int iif = 0; iif < 2; ++iif)
#pragma unroll
                for (int ks = 0; ks < 2; ++ks)
                    pa[iif][ks] = *(const bhalf8*)&Ps[(w * 32 + iif * 16 + lr) * 64 +
                                                     ((ks * 32 + lg * 8) ^ swz)];
            bhalf8 vb0[4], vb1[4];
#pragma unroll
            for (int nf = 0; nf < 4; ++nf) {
                vb0[nf] = *(const bhalf8*)&Vc[(nf * 16 + lr) * 64 + ((lg * 8) ^ swz)];
                vb1[nf] = *(const bhalf8*)&Vc[(nf * 16 + lr) * 64 + ((32 + lg * 8) ^ swz)];
            }
            __builtin_amdgcn_s_setprio(1);
#pragma unroll
            for (int nf = 0; nf < 4; ++nf)
#pragma unroll
                for (int iif = 0; iif < 2; ++iif) {
                    oacc[iif][nf] = MFMA_BF16(pa[iif][0], vb0[nf], oacc[iif][nf]);
                    oacc[iif][nf] = MFMA_BF16(pa[iif][1], vb1[nf], oacc[iif][nf]);
                }
            __builtin_amdgcn_s_setprio(0);
        }
        sync_vm0();       // next tile staged; all reads of buf[cur] done
        cur ^= 1;
    }

    // epilogue: PV waves pack into Ps (transposed layout), all threads write AO
    if (w < 4) {
#pragma unroll
        for (int iif = 0; iif < 2; ++iif)
#pragma unroll
            for (int nf = 0; nf < 4; ++nf)
#pragma unroll
                for (int r = 0; r < 4; ++r) {
                    int li  = w * 32 + iif * 16 + lg * 4 + r;
                    int dhc = (nf * 16 + lr) ^ ((li & 7) << 3);
                    Ps[li * 64 + dhc] = f2bf(oacc[iif][nf][r]);
                }
    }
    __syncthreads();
    {
        int r = t >> 2, sgq = (t & 3) * 16;
        int sz2 = (r & 7) << 3;
        ush8 v0 = *(const ush8*)&Ps[r * 64 + (sgq ^ sz2)];
        ush8 v1 = *(const ush8*)&Ps[r * 64 + ((sgq + 8) ^ sz2)];
        unsigned short* op = AOb + ((size_t)(b * NL + it * 128 + r)) * ND + h * NDH + sgq;
        *(ush8*)op = v0;
        *(ush8*)(op + 8) = v1;
    }
}

// ---------------------------------------------------------------------------
// Output projection: y[m][e] = sum_d AO[m][d]*WO[e][d] + bO[e].
// 64(m) x 128(e) tile, BK=64, 4 waves x (64m,32e). 2-phase pipelined staging.
// ---------------------------------------------------------------------------
__global__ __launch_bounds__(256, 2) void k_oproj_mfma(
    const unsigned short* __restrict__ AOb, const unsigned short* __restrict__ WOb,
    const float* __restrict__ bO, float* __restrict__ y)
{
    constexpr int CA = 64 * 64, CB = 128 * 64;
    __shared__ unsigned short As[2 * CA];    // AO rows m, dbuf
    __shared__ unsigned short Bs[2 * CB];    // WO rows e, dbuf

    const int mt = blockIdx.x;   // 0..63
    const int nt = blockIdx.y;   // 0..7
    const int t = threadIdx.x, w = t >> 6, lane = t & 63;
    const int lr = lane & 15, lg = lane >> 4;
    const int wn = w * 32;
    const int swz = (lr & 7) << 3;
    const int rA = lane >> 3, cg = (lane & 7) * 8;

    auto stage = [&](int k0, int buf) {
#pragma unroll
        for (int i = 0; i < 2; ++i) {            // A: 8 chunks, 2/wave
            int c  = w * 2 + i;
            int r  = c * 8 + rA;
            int gc = cg ^ ((r & 7) << 3);
            gload16(AOb + (size_t)(mt * 64 + r) * ND + k0 + gc, As + buf * CA + c * 512);
        }
#pragma unroll
        for (int i = 0; i < 4; ++i) {            // B: 16 chunks, 4/wave
            int c  = w * 4 + i;
            int r  = c * 8 + rA;
            int gc = cg ^ ((r & 7) << 3);
            gload16(WOb + (size_t)(nt * 128 + r) * ND + k0 + gc, Bs + buf * CB + c * 512);
        }
    };

    f32x4 acc[4][2] = {};
    stage(0, 0);
    sync_vm0();

    int cur = 0;
    for (int k0 = 0; k0 < ND; k0 += 64) {
        if (k0 + 64 < ND) stage(k0 + 64, cur ^ 1);
        const unsigned short* Ac = As + cur * CA;
        const unsigned short* Bc = Bs + cur * CB;

        bhalf8 bw[2][2];
#pragma unroll
        for (int nf = 0; nf < 2; ++nf)
#pragma unroll
            for (int ks = 0; ks < 2; ++ks)
                bw[nf][ks] = *(const bhalf8*)&Bc[(wn + nf * 16 + lr) * 64 +
                                                ((ks * 32 + lg * 8) ^ swz)];
#pragma unroll
        for (int mf = 0; mf < 4; ++mf) {
            bhalf8 a0 = *(const bhalf8*)&Ac[(mf * 16 + lr) * 64 + ((lg * 8) ^ swz)];
            bhalf8 a1 = *(const bhalf8*)&Ac[(mf * 16 + lr) * 64 + ((32 + lg * 8) ^ swz)];
#pragma unroll
            for (int nf = 0; nf < 2; ++nf) {
                acc[mf][nf] = MFMA_BF16(a0, bw[nf][0], acc[mf][nf]);
                acc[mf][nf] = MFMA_BF16(a1, bw[nf][1], acc[mf][nf]);
            }
        }
        sync_vm0();
        cur ^= 1;
    }

#pragma unroll
    for (int mf = 0; mf < 4; ++mf)
#pragma unroll
        for (int nf = 0; nf < 2; ++nf) {
            int e = nt * 128 + wn + nf * 16 + lr;
            float bo = bO[e];
#pragma unroll
            for (int r = 0; r < 4; ++r) {
                int m = mt * 64 + mf * 16 + lg * 4 + r;
                y[(size_t)m * ND + e] = acc[mf][nf][r] + bo;
            }
        }
}

// ---------------------------------------------------------------------------
extern "C" void kernel_launch(void* const* d_in, const int* in_sizes, int n_in,
                              void* d_out, int out_size, void* d_ws, size_t ws_size,
                              hipStream_t stream)
{
    const float* x  = (const float*)d_in[0];
    const float* Wq = (const float*)d_in[1];
    const float* bq = (const float*)d_in[2];
    const float* Wk = (const float*)d_in[3];
    const float* bk = (const float*)d_in[4];
    const float* Wv = (const float*)d_in[5];
    const float* bv = (const float*)d_in[6];
    const float* WO = (const float*)d_in[7];
    const float* bO = (const float*)d_in[8];
    float* y = (float*)d_out;

    unsigned short* xb  = (unsigned short*)d_ws;     // 4,194,304 (8 MB)
    unsigned short* Wtb = xb  + 4194304;             // 3,145,728 (6 MB)
    unsigned short* WOb = Wtb + 3145728;             // 1,048,576 (2 MB)
    unsigned short* Qb  = WOb + 1048576;             // 4,194,304 (8 MB)
    unsigned short* Kb  = Qb  + 4194304;             // 4,194,304 (8 MB)
    unsigned short* Vtb = Kb  + 4194304;             // 4,194,304 (8 MB)
    unsigned short* AOb = Vtb + 4194304;             // 4,194,304 (8 MB)

    hipLaunchKernelGGL(k_cvt,         dim3(2560),   dim3(256), 0, stream, x, WO, xb, WOb);
    hipLaunchKernelGGL(k_cvt_wt,      dim3(16, 48), dim3(256), 0, stream, Wq, Wk, Wv, Wtb);
    hipLaunchKernelGGL(k_qkv_mfma,    dim3(32, 24), dim3(256), 0, stream,
                       xb, Wtb, bq, bk, bv, Qb, Kb, Vtb);
    hipLaunchKernelGGL(k_colsum_mfma, dim3(16, 32), dim3(512), 0, stream, Qb, Kb, Vtb);
    hipLaunchKernelGGL(k_av_mfma,     dim3(16, 32), dim3(512), 0, stream, Qb, Kb, Vtb, AOb);
    hipLaunchKernelGGL(k_oproj_mfma,  dim3(64, 8),  dim3(256), 0, stream, AOb, WOb, bO, y);
}